// Round 6
// baseline (310.017 us; speedup 1.0000x reference)
//
#include <hip/hip_runtime.h>
#include <stdint.h>

#define T_TOK 4096
#define DM    512
#define DFF   2048
#define NE    16
#define NSLOT (T_TOK * 2)
#define NW    (NE * DFF * DM)   // 16,777,216 elems per weight tensor
#define MAXTILE 80              // max Σ ceil(cnt_e/128) = 79
#define CONVB (2 * NW / 8 / 256) // 16384 convert blocks
#define ROUTB (T_TOK / 4)        // 1024 router blocks (dispatched FIRST)
#define KSPLIT 4                 // gemm2 K-split (DFF/KSPLIT = 512 per part)

typedef __attribute__((ext_vector_type(8))) short  bf16x8;
typedef __attribute__((ext_vector_type(4))) float  f32x4;
typedef __attribute__((ext_vector_type(8))) unsigned short us8;

static __device__ __forceinline__ unsigned short f2bf(float f) {
    unsigned int u = __float_as_uint(f);
    u += 0x7FFFu + ((u >> 16) & 1u);   // RNE
    return (unsigned short)(u >> 16);
}

static __device__ __forceinline__ void gload_lds16(const void* g, void* l) {
    __builtin_amdgcn_global_load_lds(
        (const __attribute__((address_space(1))) void*)g,
        (__attribute__((address_space(3))) void*)l, 16, 0, 0);
}

// ---- fused prologue: [0,ROUTB) router ; [ROUTB,+CONVB) w1/w2 fp32->bf16 ----
// Router blocks FIRST: dispatch is ~in blockIdx order, so router's per-block
// latency retires under the convert HBM stream instead of tailing it.
// Router branch also initializes out[t] = g0*b2[e0] + g1*b2[e1]; gemm2's
// gated atomics accumulate on top. Convert uses NON-TEMPORAL fp32 loads so
// the 128 MB dead stream doesn't evict the just-written bf16 weights from L3.
__global__ __launch_bounds__(256) void convert_router_kernel(
    const float* __restrict__ w1, const float* __restrict__ w2,
    unsigned short* __restrict__ w1b, unsigned short* __restrict__ w2b,
    const float* __restrict__ x, const float* __restrict__ rw,
    const float* __restrict__ rb, int* __restrict__ tok_e,
    float* __restrict__ tok_g, unsigned short* __restrict__ xb,
    const float* __restrict__ b2, float* __restrict__ out)
{
    __shared__ float rws[NE * DM];
    int tid = threadIdx.x;

    if (blockIdx.x >= ROUTB) {
        // -------- convert branch ----
        size_t i = ((size_t)(blockIdx.x - ROUTB) * 256 + tid) * 8;
        const float* src; unsigned short* dst;
        if (i < (size_t)NW) { src = w1 + i;        dst = w1b + i; }
        else                { src = w2 + (i - NW); dst = w2b + (i - NW); }
        f32x4 a = __builtin_nontemporal_load((const f32x4*)src);
        f32x4 b = __builtin_nontemporal_load((const f32x4*)(src + 4));
        us8 v;
        v[0] = f2bf(a.x); v[1] = f2bf(a.y); v[2] = f2bf(a.z); v[3] = f2bf(a.w);
        v[4] = f2bf(b.x); v[5] = f2bf(b.y); v[6] = f2bf(b.z); v[7] = f2bf(b.w);
        *(us8*)dst = v;
        return;
    }

    // -------- router branch (identical math to verified router_kernel) ----
    for (int i = 0; i < 8; ++i) {
        int idx = (tid + i * 256) * 4;
        *(f32x4*)&rws[idx] = *(const f32x4*)&rw[idx];
    }
    __syncthreads();

    int wid = tid >> 6, lane = tid & 63;
    int t = blockIdx.x * 4 + wid;

    float xv[8];
    const float* xp = x + (size_t)t * DM + lane * 8;
    *(f32x4*)&xv[0] = *(const f32x4*)xp;
    *(f32x4*)&xv[4] = *(const f32x4*)(xp + 4);

    us8 v;
    for (int i = 0; i < 8; ++i) v[i] = f2bf(xv[i]);
    *(us8*)&xb[(size_t)t * DM + lane * 8] = v;

    float acc[NE];
    for (int e = 0; e < NE; ++e) {
        const float* wp = &rws[e * DM + lane * 8];
        float a = 0.f;
        for (int i = 0; i < 8; ++i) a += xv[i] * wp[i];
        acc[e] = a;
    }
    for (int e = 0; e < NE; ++e) {
        float v2 = acc[e];
        for (int off = 32; off > 0; off >>= 1) v2 += __shfl_xor(v2, off);
        acc[e] = v2 + rb[e];
    }
    float m = acc[0];
    for (int e = 1; e < NE; ++e) m = fmaxf(m, acc[e]);
    float p[NE]; float s = 0.f;
    for (int e = 0; e < NE; ++e) { p[e] = expf(acc[e] - m); s += p[e]; }
    float inv = 1.f / s;
    int i0 = 0; float p0 = p[0];
    for (int e = 1; e < NE; ++e) if (p[e] > p0) { p0 = p[e]; i0 = e; }
    int i1 = (i0 == 0) ? 1 : 0; float p1 = p[i1];
    for (int e = 0; e < NE; ++e)
        if (e != i0 && p[e] > p1) { p1 = p[e]; i1 = e; }
    float g0 = p0 * inv, g1 = p1 * inv;
    if (lane == 0) {
        tok_e[t * 2]     = i0;  tok_e[t * 2 + 1] = i1;
        tok_g[t * 2]     = g0;
        tok_g[t * 2 + 1] = g1;
    }
    // out init: gated biases (gemm2 atomics accumulate the matmul on top)
    {
        int d = lane * 8;
        f32x4 c0a = *(const f32x4*)&b2[i0 * DM + d];
        f32x4 c0b = *(const f32x4*)&b2[i0 * DM + d + 4];
        f32x4 c1a = *(const f32x4*)&b2[i1 * DM + d];
        f32x4 c1b = *(const f32x4*)&b2[i1 * DM + d + 4];
        f32x4 oa, ob;
        for (int i = 0; i < 4; ++i) {
            oa[i] = g0 * c0a[i] + g1 * c1a[i];
            ob[i] = g0 * c0b[i] + g1 * c1b[i];
        }
        *(f32x4*)&out[(size_t)t * DM + d]     = oa;
        *(f32x4*)&out[(size_t)t * DM + d + 4] = ob;
    }
}

// -------- compaction: deterministic hierarchical scan, no atomics --------
// eoff layout: [0..15] row offset, [16..31] count, [32..47] tile_base, [48] total_tiles
// 1024 threads; thread handles 8 entries (= 4 tokens x top-2), all counter/offset
// arrays statically indexed (unrolled) so they stay in registers (rule #20).
// Also emits slot_gate[s] (gate prob of the entry occupying slot s).
__global__ __launch_bounds__(1024) void compact_kernel(
    const int* __restrict__ tok_e, const float* __restrict__ tok_g,
    int* __restrict__ slot_token, float* __restrict__ slot_gate,
    int* __restrict__ eoff)
{
    __shared__ int wsum[16][NE];   // per-wave expert totals
    __shared__ int wbase[16][NE];  // per-wave exclusive bases
    __shared__ int ebl[NE];        // expert base offsets
    int tid = threadIdx.x;
    int wv = tid >> 6, lane = tid & 63;

    int ent[8];
    *(int4*)&ent[0] = *(const int4*)&tok_e[tid * 8];
    *(int4*)&ent[4] = *(const int4*)&tok_e[tid * 8 + 4];
    float gv[8];
    *(f32x4*)&gv[0] = *(const f32x4*)&tok_g[tid * 8];
    *(f32x4*)&gv[4] = *(const f32x4*)&tok_g[tid * 8 + 4];

    int cnt[NE], isc[NE];
#pragma unroll
    for (int e = 0; e < NE; ++e) {
        int c = 0;
#pragma unroll
        for (int i = 0; i < 8; ++i) c += (ent[i] == e) ? 1 : 0;
        int v = c;
#pragma unroll
        for (int off = 1; off < 64; off <<= 1) {
            int u = __shfl_up(v, off);
            if (lane >= off) v += u;
        }
        cnt[e] = c; isc[e] = v;     // isc = inclusive scan over lanes
    }
    if (lane == 63) {
#pragma unroll
        for (int e = 0; e < NE; ++e) wsum[wv][e] = isc[e];
    }
    __syncthreads();
    if (wv == 0 && lane < NE) {    // lane e owns expert e
        int e = lane, s = 0;
#pragma unroll
        for (int w = 0; w < 16; ++w) { wbase[w][e] = s; s += wsum[w][e]; }
        int til = (s + 127) >> 7;
        int rs = s, rt = til;      // 16-lane inclusive scans (rows, tiles)
#pragma unroll
        for (int off = 1; off < 16; off <<= 1) {
            int u1 = __shfl_up(rs, off);
            int u2 = __shfl_up(rt, off);
            if (lane >= off) { rs += u1; rt += u2; }
        }
        ebl[e] = rs - s;
        eoff[e] = rs - s;
        eoff[16 + e] = s;
        eoff[32 + e] = rt - til;
        if (e == NE - 1) eoff[48] = rt;
    }
    __syncthreads();
    int ofs[NE];
#pragma unroll
    for (int e = 0; e < NE; ++e)
        ofs[e] = ebl[e] + wbase[wv][e] + isc[e] - cnt[e];
#pragma unroll
    for (int i = 0; i < 8; ++i) {
        int ei = ent[i], s = 0;
#pragma unroll
        for (int e = 0; e < NE; ++e) if (ei == e) s = ofs[e];
        slot_token[s] = tid * 4 + (i >> 1);
        slot_gate[s]  = gv[i];
#pragma unroll
        for (int e = 0; e < NE; ++e) if (ei == e) ofs[e] = s + 1;
    }
}

// ------ GEMM1: h = gelu(x_bf[gather] @ w1b^T + b1), dense tile grid ------
__global__ __launch_bounds__(256) void gemm1_kernel(
    const unsigned short* __restrict__ xb, const unsigned short* __restrict__ w1b,
    const float* __restrict__ b1, const int* __restrict__ slot_token,
    const int* __restrict__ eoff, unsigned short* __restrict__ h)
{
    __shared__ unsigned short smem[16384];     // As[128*64] + Bs[128*64]
    __shared__ int tokrow[128];
    __shared__ int meta[49];
    unsigned short* As = smem;
    unsigned short* Bs = smem + 8192;

    int tid = threadIdx.x;
    if (tid < 49) meta[tid] = eoff[tid];
    __syncthreads();

    int slot_idx = blockIdx.y;
    if (slot_idx >= meta[48]) return;
    int e = 0;
    while (e < NE - 1 && meta[32 + e + 1] <= slot_idx) ++e;
    int mt  = slot_idx - meta[32 + e];
    int off = meta[e], cnt = meta[16 + e];
    int nB    = blockIdx.x * 128;
    int slot0 = off + mt * 128;
    int valid = cnt - mt * 128; if (valid > 128) valid = 128;

    if (tid < 128) {
        int s = slot0 + tid; if (s > NSLOT - 1) s = NSLOT - 1;
        tokrow[tid] = slot_token[s];
    }
    __syncthreads();

    f32x4 acc[16];
    for (int i = 0; i < 16; ++i) acc[i] = (f32x4){0.f, 0.f, 0.f, 0.f};

    const unsigned short* wb = w1b + ((size_t)e * DFF + nB) * DM;
    int wid = tid >> 6, l = tid & 63;
    int wm = (wid & 1) * 64, wn = (wid >> 1) * 64;
    int q = l >> 4, c = l & 15;

    for (int kt = 0; kt < DM / 64; ++kt) {
        for (int j = 0; j < 4; ++j) {
            int u = (wid * 4 + j) * 64 + l;
            int row = u >> 3, sc = (u & 7) ^ (row & 7);
            gload_lds16(xb + (size_t)tokrow[row] * DM + kt * 64 + sc * 8, &As[u * 8]);
        }
        for (int j = 0; j < 4; ++j) {
            int u = (wid * 4 + j) * 64 + l;
            int row = u >> 3, sc = (u & 7) ^ (row & 7);
            gload_lds16(wb + (size_t)row * DM + kt * 64 + sc * 8, &Bs[u * 8]);
        }
        __syncthreads();
        for (int ks = 0; ks < 2; ++ks) {
            int sw = ((ks * 4 + q) ^ (c & 7)) * 8;
            bf16x8 af[4], bv[4];
            for (int i = 0; i < 4; ++i) af[i] = *(bf16x8*)&As[(wm + i * 16 + c) * 64 + sw];
            for (int j = 0; j < 4; ++j) bv[j] = *(bf16x8*)&Bs[(wn + j * 16 + c) * 64 + sw];
            for (int i = 0; i < 4; ++i)
                for (int j = 0; j < 4; ++j)
                    acc[i * 4 + j] = __builtin_amdgcn_mfma_f32_16x16x32_bf16(
                        af[i], bv[j], acc[i * 4 + j], 0, 0, 0);
        }
        __syncthreads();
    }

    float bias[4];
    for (int j = 0; j < 4; ++j) bias[j] = b1[e * DFF + nB + wn + j * 16 + c];
    unsigned short* bounce = smem;             // [64][136] per phase
    for (int ph = 0; ph < 2; ++ph) {
        __syncthreads();
        if ((wid & 1) == ph) {
            for (int i = 0; i < 4; ++i)
                for (int j = 0; j < 4; ++j) {
                    f32x4 a = acc[i * 4 + j];
                    for (int r = 0; r < 4; ++r) {
                        int rl = i * 16 + q * 4 + r;
                        float z = a[r] + bias[j];
                        // tanh-form GELU: max |diff| vs erf-form ~5e-4,
                        // an order below the bf16 quantization of h.
                        float u2 = z * fmaf(0.0356774081f, z * z, 0.7978845608f);
                        float ex = __expf(2.0f * u2);
                        float th = 1.0f - 2.0f * __builtin_amdgcn_rcpf(ex + 1.0f);
                        float g = 0.5f * z * (1.0f + th);
                        bounce[rl * 136 + wn + j * 16 + c] = f2bf(g);
                    }
                }
        }
        __syncthreads();
        for (int it = 0; it < 4; ++it) {
            int u2 = it * 256 + tid;
            int row = u2 >> 4, ch = u2 & 15;
            int gr = ph * 64 + row;
            if (gr < valid)
                *(us8*)&h[(size_t)(slot0 + gr) * DFF + nB + ch * 8] =
                    *(us8*)&bounce[row * 136 + ch * 8];
        }
    }
}

// ------ GEMM2: split-K=KSPLIT, fused combine via gated fp32 atomics ------
// out[token(rl)] += gate(rl) * (h[rl,Kz] @ w2b[:,Kz]^T); all KSPLIT parts and
// both experts of a token accumulate onto the bias-init from the prologue.
__global__ __launch_bounds__(256) void gemm2_kernel(
    const unsigned short* __restrict__ h, const unsigned short* __restrict__ w2b,
    const int* __restrict__ eoff, const int* __restrict__ slot_token,
    const float* __restrict__ slot_gate, float* __restrict__ out)
{
    __shared__ unsigned short smem[16384];
    __shared__ int meta[49];
    __shared__ int tokrow[128];
    __shared__ float sgate[128];
    unsigned short* As = smem;
    unsigned short* Bs = smem + 8192;

    int tid = threadIdx.x;
    if (tid < 49) meta[tid] = eoff[tid];
    __syncthreads();

    int slot_idx = blockIdx.y;
    if (slot_idx >= meta[48]) return;
    int e = 0;
    while (e < NE - 1 && meta[32 + e + 1] <= slot_idx) ++e;
    int mt  = slot_idx - meta[32 + e];
    int off = meta[e], cnt = meta[16 + e];
    int nB    = blockIdx.x * 128;
    int slot0 = off + mt * 128;
    int valid = cnt - mt * 128; if (valid > 128) valid = 128;
    int z = blockIdx.z;                          // K-split part

    if (tid < 128) {
        int s = slot0 + tid; if (s > NSLOT - 1) s = NSLOT - 1;
        tokrow[tid] = slot_token[s];
        sgate[tid]  = slot_gate[s];
    }
    __syncthreads();

    f32x4 acc[16];
    for (int i = 0; i < 16; ++i) acc[i] = (f32x4){0.f, 0.f, 0.f, 0.f};

    const unsigned short* wb = w2b + ((size_t)e * DM + nB) * DFF
                             + (size_t)z * (DFF / KSPLIT);
    const unsigned short* hz = h + (size_t)z * (DFF / KSPLIT);
    int wid = tid >> 6, l = tid & 63;
    int wm = (wid & 1) * 64, wn = (wid >> 1) * 64;
    int q = l >> 4, c = l & 15;

    for (int kt = 0; kt < DFF / (64 * KSPLIT); ++kt) {   // 8 iters per part
        for (int j = 0; j < 4; ++j) {
            int u = (wid * 4 + j) * 64 + l;
            int row = u >> 3, sc = (u & 7) ^ (row & 7);
            size_t s = slot0 + row; if (s > NSLOT - 1) s = NSLOT - 1;
            gload_lds16(hz + s * DFF + kt * 64 + sc * 8, &As[u * 8]);
        }
        for (int j = 0; j < 4; ++j) {
            int u = (wid * 4 + j) * 64 + l;
            int row = u >> 3, sc = (u & 7) ^ (row & 7);
            gload_lds16(wb + (size_t)row * DFF + kt * 64 + sc * 8, &Bs[u * 8]);
        }
        __syncthreads();
        for (int ks = 0; ks < 2; ++ks) {
            int sw = ((ks * 4 + q) ^ (c & 7)) * 8;
            bf16x8 af[4], bv[4];
            for (int i = 0; i < 4; ++i) af[i] = *(bf16x8*)&As[(wm + i * 16 + c) * 64 + sw];
            for (int j = 0; j < 4; ++j) bv[j] = *(bf16x8*)&Bs[(wn + j * 16 + c) * 64 + sw];
            for (int i = 0; i < 4; ++i)
                for (int j = 0; j < 4; ++j)
                    acc[i * 4 + j] = __builtin_amdgcn_mfma_f32_16x16x32_bf16(
                        af[i], bv[j], acc[i * 4 + j], 0, 0, 0);
        }
        __syncthreads();
    }

    for (int i = 0; i < 4; ++i)
        for (int j = 0; j < 4; ++j) {
            int n = nB + wn + j * 16 + c;
            for (int r = 0; r < 4; ++r) {
                int rl = wm + i * 16 + q * 4 + r;
                if (rl < valid)
                    atomicAdd(&out[(size_t)tokrow[rl] * DM + n],
                              sgate[rl] * acc[i * 4 + j][r]);
            }
        }
}

extern "C" void kernel_launch(void* const* d_in, const int* in_sizes, int n_in,
                              void* d_out, int out_size, void* d_ws, size_t ws_size,
                              hipStream_t stream) {
    const float* x  = (const float*)d_in[0];
    const float* rw = (const float*)d_in[1];
    const float* rb = (const float*)d_in[2];
    const float* w1 = (const float*)d_in[3];
    const float* b1 = (const float*)d_in[4];
    const float* w2 = (const float*)d_in[5];
    const float* b2 = (const float*)d_in[6];
    float* out = (float*)d_out;

    char* ws = (char*)d_ws;
    size_t o = 0;
    unsigned short* h   = (unsigned short*)(ws + o); o += (size_t)NSLOT * DFF * 2;
    unsigned short* w1b = (unsigned short*)(ws + o); o += (size_t)NW * 2;
    unsigned short* w2b = (unsigned short*)(ws + o); o += (size_t)NW * 2;
    unsigned short* xb  = (unsigned short*)(ws + o); o += (size_t)T_TOK * DM * 2;
    int*   tok_e      = (int*)(ws + o);   o += (size_t)NSLOT * 4;
    float* tok_g      = (float*)(ws + o); o += (size_t)NSLOT * 4;
    int*   slot_token = (int*)(ws + o);   o += (size_t)NSLOT * 4;
    float* slot_gate  = (float*)(ws + o); o += (size_t)NSLOT * 4;
    int*   eoff       = (int*)(ws + o);

    convert_router_kernel<<<ROUTB + CONVB, 256, 0, stream>>>(
        w1, w2, w1b, w2b, x, rw, rb, tok_e, tok_g, xb, b2, out);
    compact_kernel<<<1, 1024, 0, stream>>>(
        tok_e, tok_g, slot_token, slot_gate, eoff);
    gemm1_kernel<<<dim3(DFF / 128, MAXTILE), 256, 0, stream>>>(
        xb, w1b, b1, slot_token, eoff, h);
    gemm2_kernel<<<dim3(DM / 128, MAXTILE, KSPLIT), 256, 0, stream>>>(
        h, w2b, eoff, slot_token, slot_gate, out);
}

// Round 8
// 304.150 us; speedup vs baseline: 1.0193x; 1.0193x over previous
//
#include <hip/hip_runtime.h>
#include <stdint.h>

#define T_TOK 4096
#define DM    512
#define DFF   2048
#define NE    16
#define NSLOT (T_TOK * 2)
#define NW    (NE * DFF * DM)   // 16,777,216 elems per weight tensor
#define MAXTILE 80              // max Σ ceil(cnt_e/128) = 79
#define CONVB (2 * NW / 8 / 256) // 16384 convert blocks
#define ROUTB (T_TOK / 4)        // 1024 router blocks (dispatched FIRST)
#define KSPLIT 4                 // gemm2 K-split (DFF/KSPLIT = 512 per part)

typedef __attribute__((ext_vector_type(8))) short  bf16x8;
typedef __attribute__((ext_vector_type(4))) float  f32x4;
typedef __attribute__((ext_vector_type(8))) unsigned short us8;

static __device__ __forceinline__ unsigned short f2bf(float f) {
    unsigned int u = __float_as_uint(f);
    u += 0x7FFFu + ((u >> 16) & 1u);   // RNE
    return (unsigned short)(u >> 16);
}

static __device__ __forceinline__ void gload_lds16(const void* g, void* l) {
    __builtin_amdgcn_global_load_lds(
        (const __attribute__((address_space(1))) void*)g,
        (__attribute__((address_space(3))) void*)l, 16, 0, 0);
}

// XCD-chunked logical id: consecutive workgroup ids round-robin across the 8
// XCDs, so give XCD k a CONTIGUOUS chunk of the real logical work [0,total).
// Siblings of one tile (16 blocks sharing an A-tile) become L2-local, and
// same-expert adjacent tiles reuse the B panel in the same L2. Balanced on
// the device-known real total; leftover hw slots return logical=total (exit).
static __device__ __forceinline__ int xcd_chunk_logical(int bid, int total) {
    int k = bid & 7, seq = bid >> 3;
    int q = total >> 3, r = total & 7;
    int base = k * q + (k < r ? k : r);
    int len  = q + (k < r ? 1 : 0);
    return (seq < len) ? (base + seq) : total;
}

// ---- fused prologue: [0,ROUTB) router ; [ROUTB,+CONVB) w1/w2 fp32->bf16 ----
// Router blocks FIRST: dispatch is ~in blockIdx order, so router's per-block
// latency retires under the convert HBM stream instead of tailing it.
// Router branch also initializes out[t] = g0*b2[e0] + g1*b2[e1]; gemm2's
// gated atomics accumulate on top. Convert uses NON-TEMPORAL fp32 loads so
// the 128 MB dead stream doesn't evict the just-written bf16 weights from L3.
__global__ __launch_bounds__(256) void convert_router_kernel(
    const float* __restrict__ w1, const float* __restrict__ w2,
    unsigned short* __restrict__ w1b, unsigned short* __restrict__ w2b,
    const float* __restrict__ x, const float* __restrict__ rw,
    const float* __restrict__ rb, int* __restrict__ tok_e,
    float* __restrict__ tok_g, unsigned short* __restrict__ xb,
    const float* __restrict__ b2, float* __restrict__ out)
{
    __shared__ float rws[NE * DM];
    int tid = threadIdx.x;

    if (blockIdx.x >= ROUTB) {
        // -------- convert branch ----
        size_t i = ((size_t)(blockIdx.x - ROUTB) * 256 + tid) * 8;
        const float* src; unsigned short* dst;
        if (i < (size_t)NW) { src = w1 + i;        dst = w1b + i; }
        else                { src = w2 + (i - NW); dst = w2b + (i - NW); }
        f32x4 a = __builtin_nontemporal_load((const f32x4*)src);
        f32x4 b = __builtin_nontemporal_load((const f32x4*)(src + 4));
        us8 v;
        v[0] = f2bf(a.x); v[1] = f2bf(a.y); v[2] = f2bf(a.z); v[3] = f2bf(a.w);
        v[4] = f2bf(b.x); v[5] = f2bf(b.y); v[6] = f2bf(b.z); v[7] = f2bf(b.w);
        *(us8*)dst = v;
        return;
    }

    // -------- router branch (identical math to verified router_kernel) ----
    for (int i = 0; i < 8; ++i) {
        int idx = (tid + i * 256) * 4;
        *(f32x4*)&rws[idx] = *(const f32x4*)&rw[idx];
    }
    __syncthreads();

    int wid = tid >> 6, lane = tid & 63;
    int t = blockIdx.x * 4 + wid;

    float xv[8];
    const float* xp = x + (size_t)t * DM + lane * 8;
    *(f32x4*)&xv[0] = *(const f32x4*)xp;
    *(f32x4*)&xv[4] = *(const f32x4*)(xp + 4);

    us8 v;
    for (int i = 0; i < 8; ++i) v[i] = f2bf(xv[i]);
    *(us8*)&xb[(size_t)t * DM + lane * 8] = v;

    float acc[NE];
    for (int e = 0; e < NE; ++e) {
        const float* wp = &rws[e * DM + lane * 8];
        float a = 0.f;
        for (int i = 0; i < 8; ++i) a += xv[i] * wp[i];
        acc[e] = a;
    }
    for (int e = 0; e < NE; ++e) {
        float v2 = acc[e];
        for (int off = 32; off > 0; off >>= 1) v2 += __shfl_xor(v2, off);
        acc[e] = v2 + rb[e];
    }
    float m = acc[0];
    for (int e = 1; e < NE; ++e) m = fmaxf(m, acc[e]);
    float p[NE]; float s = 0.f;
    for (int e = 0; e < NE; ++e) { p[e] = expf(acc[e] - m); s += p[e]; }
    float inv = 1.f / s;
    int i0 = 0; float p0 = p[0];
    for (int e = 1; e < NE; ++e) if (p[e] > p0) { p0 = p[e]; i0 = e; }
    int i1 = (i0 == 0) ? 1 : 0; float p1 = p[i1];
    for (int e = 0; e < NE; ++e)
        if (e != i0 && p[e] > p1) { p1 = p[e]; i1 = e; }
    float g0 = p0 * inv, g1 = p1 * inv;
    if (lane == 0) {
        tok_e[t * 2]     = i0;  tok_e[t * 2 + 1] = i1;
        tok_g[t * 2]     = g0;
        tok_g[t * 2 + 1] = g1;
    }
    // out init: gated biases (gemm2 atomics accumulate the matmul on top)
    {
        int d = lane * 8;
        f32x4 c0a = *(const f32x4*)&b2[i0 * DM + d];
        f32x4 c0b = *(const f32x4*)&b2[i0 * DM + d + 4];
        f32x4 c1a = *(const f32x4*)&b2[i1 * DM + d];
        f32x4 c1b = *(const f32x4*)&b2[i1 * DM + d + 4];
        f32x4 oa, ob;
        for (int i = 0; i < 4; ++i) {
            oa[i] = g0 * c0a[i] + g1 * c1a[i];
            ob[i] = g0 * c0b[i] + g1 * c1b[i];
        }
        *(f32x4*)&out[(size_t)t * DM + d]     = oa;
        *(f32x4*)&out[(size_t)t * DM + d + 4] = ob;
    }
}

// -------- compaction: deterministic hierarchical scan, no atomics --------
// eoff layout: [0..15] row offset, [16..31] count, [32..47] tile_base, [48] total_tiles
// 1024 threads; thread handles 8 entries (= 4 tokens x top-2), all counter/offset
// arrays statically indexed (unrolled) so they stay in registers (rule #20).
// Also emits slot_gate[s] (gate prob of the entry occupying slot s).
__global__ __launch_bounds__(1024) void compact_kernel(
    const int* __restrict__ tok_e, const float* __restrict__ tok_g,
    int* __restrict__ slot_token, float* __restrict__ slot_gate,
    int* __restrict__ eoff)
{
    __shared__ int wsum[16][NE];   // per-wave expert totals
    __shared__ int wbase[16][NE];  // per-wave exclusive bases
    __shared__ int ebl[NE];        // expert base offsets
    int tid = threadIdx.x;
    int wv = tid >> 6, lane = tid & 63;

    int ent[8];
    *(int4*)&ent[0] = *(const int4*)&tok_e[tid * 8];
    *(int4*)&ent[4] = *(const int4*)&tok_e[tid * 8 + 4];
    float gv[8];
    *(f32x4*)&gv[0] = *(const f32x4*)&tok_g[tid * 8];
    *(f32x4*)&gv[4] = *(const f32x4*)&tok_g[tid * 8 + 4];

    int cnt[NE], isc[NE];
#pragma unroll
    for (int e = 0; e < NE; ++e) {
        int c = 0;
#pragma unroll
        for (int i = 0; i < 8; ++i) c += (ent[i] == e) ? 1 : 0;
        int v = c;
#pragma unroll
        for (int off = 1; off < 64; off <<= 1) {
            int u = __shfl_up(v, off);
            if (lane >= off) v += u;
        }
        cnt[e] = c; isc[e] = v;     // isc = inclusive scan over lanes
    }
    if (lane == 63) {
#pragma unroll
        for (int e = 0; e < NE; ++e) wsum[wv][e] = isc[e];
    }
    __syncthreads();
    if (wv == 0 && lane < NE) {    // lane e owns expert e
        int e = lane, s = 0;
#pragma unroll
        for (int w = 0; w < 16; ++w) { wbase[w][e] = s; s += wsum[w][e]; }
        int til = (s + 127) >> 7;
        int rs = s, rt = til;      // 16-lane inclusive scans (rows, tiles)
#pragma unroll
        for (int off = 1; off < 16; off <<= 1) {
            int u1 = __shfl_up(rs, off);
            int u2 = __shfl_up(rt, off);
            if (lane >= off) { rs += u1; rt += u2; }
        }
        ebl[e] = rs - s;
        eoff[e] = rs - s;
        eoff[16 + e] = s;
        eoff[32 + e] = rt - til;
        if (e == NE - 1) eoff[48] = rt;
    }
    __syncthreads();
    int ofs[NE];
#pragma unroll
    for (int e = 0; e < NE; ++e)
        ofs[e] = ebl[e] + wbase[wv][e] + isc[e] - cnt[e];
#pragma unroll
    for (int i = 0; i < 8; ++i) {
        int ei = ent[i], s = 0;
#pragma unroll
        for (int e = 0; e < NE; ++e) if (ei == e) s = ofs[e];
        slot_token[s] = tid * 4 + (i >> 1);
        slot_gate[s]  = gv[i];
#pragma unroll
        for (int e = 0; e < NE; ++e) if (ei == e) ofs[e] = s + 1;
    }
}

// ------ GEMM1: h = gelu(x_bf[gather] @ w1b^T + b1), XCD-chunked 1-D grid --
__global__ __launch_bounds__(256) void gemm1_kernel(
    const unsigned short* __restrict__ xb, const unsigned short* __restrict__ w1b,
    const float* __restrict__ b1, const int* __restrict__ slot_token,
    const int* __restrict__ eoff, unsigned short* __restrict__ h)
{
    __shared__ unsigned short smem[16384];     // As[128*64] + Bs[128*64]
    __shared__ int tokrow[128];
    __shared__ int meta[49];
    unsigned short* As = smem;
    unsigned short* Bs = smem + 8192;

    int tid = threadIdx.x;
    if (tid < 49) meta[tid] = eoff[tid];
    __syncthreads();

    // logical = tile*16 + n ; 16 n-siblings of a tile share the A-tile and
    // stay in one XCD's L2; same-expert adjacent tiles reuse the B panel.
    int lg = xcd_chunk_logical(blockIdx.x, meta[48] * 16);
    int slot_idx = lg >> 4;
    if (slot_idx >= meta[48]) return;
    int nB = (lg & 15) * 128;
    int e = 0;
    while (e < NE - 1 && meta[32 + e + 1] <= slot_idx) ++e;
    int mt  = slot_idx - meta[32 + e];
    int off = meta[e], cnt = meta[16 + e];
    int slot0 = off + mt * 128;
    int valid = cnt - mt * 128; if (valid > 128) valid = 128;

    if (tid < 128) {
        int s = slot0 + tid; if (s > NSLOT - 1) s = NSLOT - 1;
        tokrow[tid] = slot_token[s];
    }
    __syncthreads();

    f32x4 acc[16];
    for (int i = 0; i < 16; ++i) acc[i] = (f32x4){0.f, 0.f, 0.f, 0.f};

    const unsigned short* wb = w1b + ((size_t)e * DFF + nB) * DM;
    int wid = tid >> 6, l = tid & 63;
    int wm = (wid & 1) * 64, wn = (wid >> 1) * 64;
    int q = l >> 4, c = l & 15;

    for (int kt = 0; kt < DM / 64; ++kt) {
        for (int j = 0; j < 4; ++j) {
            int u = (wid * 4 + j) * 64 + l;
            int row = u >> 3, sc = (u & 7) ^ (row & 7);
            gload_lds16(xb + (size_t)tokrow[row] * DM + kt * 64 + sc * 8, &As[u * 8]);
        }
        for (int j = 0; j < 4; ++j) {
            int u = (wid * 4 + j) * 64 + l;
            int row = u >> 3, sc = (u & 7) ^ (row & 7);
            gload_lds16(wb + (size_t)row * DM + kt * 64 + sc * 8, &Bs[u * 8]);
        }
        __syncthreads();
        for (int ks = 0; ks < 2; ++ks) {
            int sw = ((ks * 4 + q) ^ (c & 7)) * 8;
            bf16x8 af[4], bv[4];
            for (int i = 0; i < 4; ++i) af[i] = *(bf16x8*)&As[(wm + i * 16 + c) * 64 + sw];
            for (int j = 0; j < 4; ++j) bv[j] = *(bf16x8*)&Bs[(wn + j * 16 + c) * 64 + sw];
            for (int i = 0; i < 4; ++i)
                for (int j = 0; j < 4; ++j)
                    acc[i * 4 + j] = __builtin_amdgcn_mfma_f32_16x16x32_bf16(
                        af[i], bv[j], acc[i * 4 + j], 0, 0, 0);
        }
        __syncthreads();
    }

    float bias[4];
    for (int j = 0; j < 4; ++j) bias[j] = b1[e * DFF + nB + wn + j * 16 + c];
    unsigned short* bounce = smem;             // [64][136] per phase
    for (int ph = 0; ph < 2; ++ph) {
        __syncthreads();
        if ((wid & 1) == ph) {
            for (int i = 0; i < 4; ++i)
                for (int j = 0; j < 4; ++j) {
                    f32x4 a = acc[i * 4 + j];
                    for (int r = 0; r < 4; ++r) {
                        int rl = i * 16 + q * 4 + r;
                        float z = a[r] + bias[j];
                        // tanh-form GELU: max |diff| vs erf-form ~5e-4,
                        // an order below the bf16 quantization of h.
                        float u2 = z * fmaf(0.0356774081f, z * z, 0.7978845608f);
                        float ex = __expf(2.0f * u2);
                        float th = 1.0f - 2.0f * __builtin_amdgcn_rcpf(ex + 1.0f);
                        float g = 0.5f * z * (1.0f + th);
                        bounce[rl * 136 + wn + j * 16 + c] = f2bf(g);
                    }
                }
        }
        __syncthreads();
        for (int it = 0; it < 4; ++it) {
            int u2 = it * 256 + tid;
            int row = u2 >> 4, ch = u2 & 15;
            int gr = ph * 64 + row;
            if (gr < valid)
                *(us8*)&h[(size_t)(slot0 + gr) * DFF + nB + ch * 8] =
                    *(us8*)&bounce[row * 136 + ch * 8];
        }
    }
}

// ------ GEMM2: split-K=KSPLIT, fused combine via gated fp32 atomics ------
// out[token(rl)] += gate(rl) * (h[rl,Kz] @ w2b[:,Kz]^T); all KSPLIT parts and
// both experts of a token accumulate onto the bias-init from the prologue.
__global__ __launch_bounds__(256) void gemm2_kernel(
    const unsigned short* __restrict__ h, const unsigned short* __restrict__ w2b,
    const int* __restrict__ eoff, const int* __restrict__ slot_token,
    const float* __restrict__ slot_gate, float* __restrict__ out)
{
    __shared__ unsigned short smem[16384];
    __shared__ int meta[49];
    __shared__ int tokrow[128];
    __shared__ float sgate[128];
    unsigned short* As = smem;
    unsigned short* Bs = smem + 8192;

    int tid = threadIdx.x;
    if (tid < 49) meta[tid] = eoff[tid];
    __syncthreads();

    // logical = tile*16 + z*4 + n ; the 16 siblings (4n x 4z) of one tile
    // share A-rows (per z) and together cover the expert's B panel — all in
    // one XCD's L2; adjacent same-expert tiles then reuse that B panel.
    int lg = xcd_chunk_logical(blockIdx.x, meta[48] * 16);
    int slot_idx = lg >> 4;
    if (slot_idx >= meta[48]) return;
    int nB = (lg & 3) * 128;
    int z  = (lg >> 2) & 3;                      // K-split part
    int e = 0;
    while (e < NE - 1 && meta[32 + e + 1] <= slot_idx) ++e;
    int mt  = slot_idx - meta[32 + e];
    int off = meta[e], cnt = meta[16 + e];
    int slot0 = off + mt * 128;
    int valid = cnt - mt * 128; if (valid > 128) valid = 128;

    if (tid < 128) {
        int s = slot0 + tid; if (s > NSLOT - 1) s = NSLOT - 1;
        tokrow[tid] = slot_token[s];
        sgate[tid]  = slot_gate[s];
    }
    __syncthreads();

    f32x4 acc[16];
    for (int i = 0; i < 16; ++i) acc[i] = (f32x4){0.f, 0.f, 0.f, 0.f};

    const unsigned short* wb = w2b + ((size_t)e * DM + nB) * DFF
                             + (size_t)z * (DFF / KSPLIT);
    const unsigned short* hz = h + (size_t)z * (DFF / KSPLIT);
    int wid = tid >> 6, l = tid & 63;
    int wm = (wid & 1) * 64, wn = (wid >> 1) * 64;
    int q = l >> 4, c = l & 15;

    for (int kt = 0; kt < DFF / (64 * KSPLIT); ++kt) {   // 8 iters per part
        for (int j = 0; j < 4; ++j) {
            int u = (wid * 4 + j) * 64 + l;
            int row = u >> 3, sc = (u & 7) ^ (row & 7);
            size_t s = slot0 + row; if (s > NSLOT - 1) s = NSLOT - 1;
            gload_lds16(hz + s * DFF + kt * 64 + sc * 8, &As[u * 8]);
        }
        for (int j = 0; j < 4; ++j) {
            int u = (wid * 4 + j) * 64 + l;
            int row = u >> 3, sc = (u & 7) ^ (row & 7);
            gload_lds16(wb + (size_t)row * DFF + kt * 64 + sc * 8, &Bs[u * 8]);
        }
        __syncthreads();
        for (int ks = 0; ks < 2; ++ks) {
            int sw = ((ks * 4 + q) ^ (c & 7)) * 8;
            bf16x8 af[4], bv[4];
            for (int i = 0; i < 4; ++i) af[i] = *(bf16x8*)&As[(wm + i * 16 + c) * 64 + sw];
            for (int j = 0; j < 4; ++j) bv[j] = *(bf16x8*)&Bs[(wn + j * 16 + c) * 64 + sw];
            for (int i = 0; i < 4; ++i)
                for (int j = 0; j < 4; ++j)
                    acc[i * 4 + j] = __builtin_amdgcn_mfma_f32_16x16x32_bf16(
                        af[i], bv[j], acc[i * 4 + j], 0, 0, 0);
        }
        __syncthreads();
    }

    for (int i = 0; i < 4; ++i)
        for (int j = 0; j < 4; ++j) {
            int n = nB + wn + j * 16 + c;
            for (int r = 0; r < 4; ++r) {
                int rl = wm + i * 16 + q * 4 + r;
                if (rl < valid)
                    atomicAdd(&out[(size_t)tokrow[rl] * DM + n],
                              sgate[rl] * acc[i * 4 + j][r]);
            }
        }
}

extern "C" void kernel_launch(void* const* d_in, const int* in_sizes, int n_in,
                              void* d_out, int out_size, void* d_ws, size_t ws_size,
                              hipStream_t stream) {
    const float* x  = (const float*)d_in[0];
    const float* rw = (const float*)d_in[1];
    const float* rb = (const float*)d_in[2];
    const float* w1 = (const float*)d_in[3];
    const float* b1 = (const float*)d_in[4];
    const float* w2 = (const float*)d_in[5];
    const float* b2 = (const float*)d_in[6];
    float* out = (float*)d_out;

    char* ws = (char*)d_ws;
    size_t o = 0;
    unsigned short* h   = (unsigned short*)(ws + o); o += (size_t)NSLOT * DFF * 2;
    unsigned short* w1b = (unsigned short*)(ws + o); o += (size_t)NW * 2;
    unsigned short* w2b = (unsigned short*)(ws + o); o += (size_t)NW * 2;
    unsigned short* xb  = (unsigned short*)(ws + o); o += (size_t)T_TOK * DM * 2;
    int*   tok_e      = (int*)(ws + o);   o += (size_t)NSLOT * 4;
    float* tok_g      = (float*)(ws + o); o += (size_t)NSLOT * 4;
    int*   slot_token = (int*)(ws + o);   o += (size_t)NSLOT * 4;
    float* slot_gate  = (float*)(ws + o); o += (size_t)NSLOT * 4;
    int*   eoff       = (int*)(ws + o);

    convert_router_kernel<<<ROUTB + CONVB, 256, 0, stream>>>(
        w1, w2, w1b, w2b, x, rw, rb, tok_e, tok_g, xb, b2, out);
    compact_kernel<<<1, 1024, 0, stream>>>(
        tok_e, tok_g, slot_token, slot_gate, eoff);
    gemm1_kernel<<<16 * MAXTILE, 256, 0, stream>>>(
        xb, w1b, b1, slot_token, eoff, h);
    gemm2_kernel<<<4 * MAXTILE * KSPLIT, 256, 0, stream>>>(
        h, w2b, eoff, slot_token, slot_gate, out);
}